// Round 7
// baseline (46.925 us; speedup 1.0000x reference)
//
#include <hip/hip_runtime.h>
#include <math.h>

#define FEAT 64
#define SEGS_PER_BLOCK 4

typedef float floatx4 __attribute__((ext_vector_type(4)));
typedef unsigned int uintx4 __attribute__((ext_vector_type(4)));
typedef int intx4 __attribute__((ext_vector_type(4)));

static __device__ __forceinline__ ushort f32_to_bf16_rne(float f) {
    uint32_t u = __float_as_uint(f);
    uint32_t r = (u + 0x7fffu + ((u >> 16) & 1u)) >> 16;
    return (ushort)r;
}

// Fused pre-pass: blocks [0, conv_blocks) convert features fp32->bf16 (RNE);
// remaining blocks compute segment run starts from the sorted segment_ids.
// All dead-after-use streams are non-temporal to keep L2 clean for the table.
__global__ __launch_bounds__(256)
void pre_kernel(const float* __restrict__ feat,
                const int* __restrict__ segment_ids,
                ushort* __restrict__ feat_bf,
                int* __restrict__ starts,
                int conv_blocks, int n_elems, int n_members, int num_segments) {
    if ((int)blockIdx.x < conv_blocks) {
        const int e0 = (blockIdx.x * 256 + threadIdx.x) << 3;
        if (e0 < n_elems) {  // n_elems is a multiple of 8 (FEAT=64)
            const floatx4* p = (const floatx4*)(feat + e0);
            const floatx4 a = __builtin_nontemporal_load(p);
            const floatx4 b = __builtin_nontemporal_load(p + 1);
            uintx4 o;
            o.x = (uint)f32_to_bf16_rne(a.x) | ((uint)f32_to_bf16_rne(a.y) << 16);
            o.y = (uint)f32_to_bf16_rne(a.z) | ((uint)f32_to_bf16_rne(a.w) << 16);
            o.z = (uint)f32_to_bf16_rne(b.x) | ((uint)f32_to_bf16_rne(b.y) << 16);
            o.w = (uint)f32_to_bf16_rne(b.z) | ((uint)f32_to_bf16_rne(b.w) << 16);
            *(uintx4*)(feat_bf + e0) = o;
        }
    } else {
        const int t  = (blockIdx.x - conv_blocks) * 256 + threadIdx.x;
        const int j0 = t << 2;
        if (j0 >= n_members) return;
        const intx4 s4 = __builtin_nontemporal_load((const intx4*)(segment_ids + j0));
        int prev = (j0 == 0) ? -1 : segment_ids[j0 - 1];
        const int vals[4] = {s4.x, s4.y, s4.z, s4.w};
        #pragma unroll
        for (int k = 0; k < 4; ++k) {
            const int j = j0 + k;
            if (j < n_members) {
                const int sj = vals[k];
                for (int s = prev + 1; s <= sj; ++s) starts[s] = j;
                prev = sj;
            }
        }
        if (j0 + 4 >= n_members) {
            for (int s = prev + 1; s <= num_segments; ++s) starts[s] = n_members;
        }
    }
}

// Main (R4 structure): one wave per segment, full grid. lane>>3 = member slot
// (8 rows = 8 x 128B lines in flight per load instr), lane&7 = 16B bf16 chunk.
// node_ids loads and out stores are non-temporal (single-use streams) so they
// don't evict the bf16 table from the per-XCD L2s.
__global__ __launch_bounds__(64 * SEGS_PER_BLOCK)
void HyperedgeMaxAggregator_kernel(const ushort* __restrict__ feat_bf,
                                   const int* __restrict__ node_ids,
                                   const int* __restrict__ starts,
                                   float* __restrict__ out,
                                   int num_segments) {
    const int wave = threadIdx.x >> 6;
    const int lane = threadIdx.x & 63;
    const int seg  = blockIdx.x * SEGS_PER_BLOCK + wave;
    if (seg >= num_segments) return;

    const int st = starts[seg];
    const int en = starts[seg + 1];

    const int mslot = lane >> 3;        // member slot 0..7
    const int fo    = (lane & 7) << 3;  // bf16 element offset (8 elems = 16B)

    float acc[8];
    #pragma unroll
    for (int k = 0; k < 8; ++k) acc[k] = -INFINITY;

    int base = st;
    int cnt  = en - st;
    while (cnt > 0) {
        const int take = (cnt < 64) ? cnt : 64;   // wave-uniform
        const int myid = (lane < take)
            ? __builtin_nontemporal_load(node_ids + base + lane) : 0;
        #pragma unroll
        for (int s = 0; s < 8; ++s) {
            const int j  = (s << 3) + mslot;
            const int id = __shfl(myid, j, 64);   // j>=take -> id 0 (hot line)
            const uint4 v = *(const uint4*)(feat_bf + (size_t)id * FEAT + fo);
            if (j < take) {
                const uint w[4] = {v.x, v.y, v.z, v.w};
                #pragma unroll
                for (int q = 0; q < 4; ++q) {
                    acc[2*q]   = fmaxf(acc[2*q],   __uint_as_float(w[q] << 16));
                    acc[2*q+1] = fmaxf(acc[2*q+1], __uint_as_float(w[q] & 0xffff0000u));
                }
            }
        }
        base += take;
        cnt  -= take;
    }

    // Reduce across the 8 member slots (lane bits 3,4,5).
    #pragma unroll
    for (int d = 8; d <= 32; d <<= 1) {
        #pragma unroll
        for (int k = 0; k < 8; ++k) {
            acc[k] = fmaxf(acc[k], __shfl_xor(acc[k], d, 64));
        }
    }

    if (lane < 8) {
        float* op = out + (size_t)seg * FEAT + (lane << 3);
        floatx4 lo = {acc[0], acc[1], acc[2], acc[3]};
        floatx4 hi = {acc[4], acc[5], acc[6], acc[7]};
        __builtin_nontemporal_store(lo, (floatx4*)op);
        __builtin_nontemporal_store(hi, (floatx4*)(op + 4));
    }
}

// ---------- fp32 fallback path (used only if ws is too small) ----------
__global__ __launch_bounds__(256)
void seg_starts_kernel(const int* __restrict__ segment_ids,
                       int* __restrict__ starts,
                       int n_members, int num_segments) {
    const int j = blockIdx.x * blockDim.x + threadIdx.x;
    if (j >= n_members) return;
    const int sj = segment_ids[j];
    const int sp = (j == 0) ? -1 : segment_ids[j - 1];
    for (int s = sp + 1; s <= sj; ++s) starts[s] = j;
    if (j == n_members - 1) {
        for (int s = sj + 1; s <= num_segments; ++s) starts[s] = n_members;
    }
}

__global__ __launch_bounds__(64 * SEGS_PER_BLOCK)
void hyper_max_f32(const float* __restrict__ features,
                   const int* __restrict__ node_ids,
                   const int* __restrict__ starts,
                   float* __restrict__ out,
                   int num_segments) {
    const int wave = threadIdx.x >> 6;
    const int lane = threadIdx.x & 63;
    const int seg  = blockIdx.x * SEGS_PER_BLOCK + wave;
    if (seg >= num_segments) return;
    const int start = starts[seg];
    const int end   = starts[seg + 1];
    const int mslot = lane >> 4;
    const int fq    = (lane & 15) << 2;
    float4 acc = make_float4(-INFINITY, -INFINITY, -INFINITY, -INFINITY);
    for (int j = start + mslot; j < end; j += 4) {
        const int n0 = node_ids[j];
        const float4 v = *(const float4*)(features + (size_t)n0 * FEAT + fq);
        acc.x = fmaxf(acc.x, v.x); acc.y = fmaxf(acc.y, v.y);
        acc.z = fmaxf(acc.z, v.z); acc.w = fmaxf(acc.w, v.w);
    }
    acc.x = fmaxf(acc.x, __shfl_xor(acc.x, 16, 64));
    acc.y = fmaxf(acc.y, __shfl_xor(acc.y, 16, 64));
    acc.z = fmaxf(acc.z, __shfl_xor(acc.z, 16, 64));
    acc.w = fmaxf(acc.w, __shfl_xor(acc.w, 16, 64));
    acc.x = fmaxf(acc.x, __shfl_xor(acc.x, 32, 64));
    acc.y = fmaxf(acc.y, __shfl_xor(acc.y, 32, 64));
    acc.z = fmaxf(acc.z, __shfl_xor(acc.z, 32, 64));
    acc.w = fmaxf(acc.w, __shfl_xor(acc.w, 32, 64));
    if (lane < 16) *(float4*)(out + (size_t)seg * FEAT + fq) = acc;
}

extern "C" void kernel_launch(void* const* d_in, const int* in_sizes, int n_in,
                              void* d_out, int out_size, void* d_ws, size_t ws_size,
                              hipStream_t stream) {
    const float* features    = (const float*)d_in[0];
    const int*   node_ids    = (const int*)d_in[1];
    const int*   segment_ids = (const int*)d_in[2];
    float* out = (float*)d_out;

    const int n_elems      = in_sizes[0];         // N_NODES * FEAT
    const int n_members    = in_sizes[1];
    const int num_segments = out_size / FEAT;

    const size_t starts_bytes = (((size_t)(num_segments + 1) * 4) + 255) & ~(size_t)255;
    const size_t bf_bytes     = (size_t)n_elems * 2;
    int* starts = (int*)d_ws;

    const int seg_blocks = (num_segments + SEGS_PER_BLOCK - 1) / SEGS_PER_BLOCK;

    if (ws_size >= starts_bytes + bf_bytes) {
        ushort* feat_bf = (ushort*)((char*)d_ws + starts_bytes);
        const int conv_blocks   = ((n_elems >> 3) + 255) / 256;
        const int starts_blocks = (((n_members + 3) >> 2) + 255) / 256;
        pre_kernel<<<conv_blocks + starts_blocks, 256, 0, stream>>>(
            features, segment_ids, feat_bf, starts,
            conv_blocks, n_elems, n_members, num_segments);
        HyperedgeMaxAggregator_kernel<<<seg_blocks, 64 * SEGS_PER_BLOCK, 0, stream>>>(
            feat_bf, node_ids, starts, out, num_segments);
    } else {
        seg_starts_kernel<<<(n_members + 255) / 256, 256, 0, stream>>>(
            segment_ids, starts, n_members, num_segments);
        hyper_max_f32<<<seg_blocks, 64 * SEGS_PER_BLOCK, 0, stream>>>(
            features, node_ids, starts, out, num_segments);
    }
}

// Round 8
// 39.817 us; speedup vs baseline: 1.1785x; 1.1785x over previous
//
#include <hip/hip_runtime.h>
#include <math.h>

#define FEAT 64
#define SEGS_PER_BLOCK 4

static __device__ __forceinline__ ushort f32_to_bf16_rne(float f) {
    uint32_t u = __float_as_uint(f);
    uint32_t r = (u + 0x7fffu + ((u >> 16) & 1u)) >> 16;
    return (ushort)r;
}

// Fused pre-pass: blocks [0, conv_blocks) convert features fp32->bf16 (RNE);
// remaining blocks compute segment run starts from the sorted segment_ids.
// NOTE: no non-temporal hints — measured regression on gfx950 (R6/R7).
__global__ __launch_bounds__(256)
void pre_kernel(const float* __restrict__ feat,
                const int* __restrict__ segment_ids,
                ushort* __restrict__ feat_bf,
                int* __restrict__ starts,
                int conv_blocks, int n_elems, int n_members, int num_segments) {
    if ((int)blockIdx.x < conv_blocks) {
        const int e0 = (blockIdx.x * 256 + threadIdx.x) << 3;
        if (e0 < n_elems) {  // n_elems is a multiple of 8 (FEAT=64)
            const float4 a = *(const float4*)(feat + e0);
            const float4 b = *(const float4*)(feat + e0 + 4);
            uint4 o;
            o.x = (uint)f32_to_bf16_rne(a.x) | ((uint)f32_to_bf16_rne(a.y) << 16);
            o.y = (uint)f32_to_bf16_rne(a.z) | ((uint)f32_to_bf16_rne(a.w) << 16);
            o.z = (uint)f32_to_bf16_rne(b.x) | ((uint)f32_to_bf16_rne(b.y) << 16);
            o.w = (uint)f32_to_bf16_rne(b.z) | ((uint)f32_to_bf16_rne(b.w) << 16);
            *(uint4*)(feat_bf + e0) = o;
        }
    } else {
        const int t  = (blockIdx.x - conv_blocks) * 256 + threadIdx.x;
        const int j0 = t << 2;
        if (j0 >= n_members) return;
        const int4 s4 = *(const int4*)(segment_ids + j0);
        int prev = (j0 == 0) ? -1 : segment_ids[j0 - 1];
        const int vals[4] = {s4.x, s4.y, s4.z, s4.w};
        #pragma unroll
        for (int k = 0; k < 4; ++k) {
            const int j = j0 + k;
            if (j < n_members) {
                const int sj = vals[k];
                for (int s = prev + 1; s <= sj; ++s) starts[s] = j;
                prev = sj;
            }
        }
        if (j0 + 4 >= n_members) {
            for (int s = prev + 1; s <= num_segments; ++s) starts[s] = n_members;
        }
    }
}

// Main: one wave per segment. lane>>3 = member slot (8 rows = 8 x 128B lines
// in flight per step), lane&7 = 16B bf16 chunk of row. Step count is
// wave-uniform and dynamic: ceil(take/8) steps instead of a fixed 8, so a
// 20-member segment issues 3 gather steps, not 8 (junk loads occupied vmcnt
// queue slots that real misses drained behind).
__global__ __launch_bounds__(64 * SEGS_PER_BLOCK)
void HyperedgeMaxAggregator_kernel(const ushort* __restrict__ feat_bf,
                                   const int* __restrict__ node_ids,
                                   const int* __restrict__ starts,
                                   float* __restrict__ out,
                                   int num_segments) {
    const int wave = threadIdx.x >> 6;
    const int lane = threadIdx.x & 63;
    const int seg  = blockIdx.x * SEGS_PER_BLOCK + wave;
    if (seg >= num_segments) return;

    const int st = starts[seg];
    const int en = starts[seg + 1];

    const int mslot = lane >> 3;        // member slot 0..7
    const int fo    = (lane & 7) << 3;  // bf16 element offset (8 elems = 16B)

    float acc[8];
    #pragma unroll
    for (int k = 0; k < 8; ++k) acc[k] = -INFINITY;

    int base = st;
    int cnt  = en - st;
    while (cnt > 0) {
        const int take  = (cnt < 64) ? cnt : 64;   // wave-uniform
        const int steps = (take + 7) >> 3;         // wave-uniform
        const int myid  = (lane < take) ? node_ids[base + lane] : 0;
        #pragma unroll 4
        for (int s = 0; s < steps; ++s) {
            const int j  = (s << 3) + mslot;
            const int id = __shfl(myid, j, 64);    // j>=take -> id 0 (hot line)
            const uint4 v = *(const uint4*)(feat_bf + (size_t)id * FEAT + fo);
            if (j < take) {
                const uint w[4] = {v.x, v.y, v.z, v.w};
                #pragma unroll
                for (int q = 0; q < 4; ++q) {
                    acc[2*q]   = fmaxf(acc[2*q],   __uint_as_float(w[q] << 16));
                    acc[2*q+1] = fmaxf(acc[2*q+1], __uint_as_float(w[q] & 0xffff0000u));
                }
            }
        }
        base += take;
        cnt  -= take;
    }

    // Reduce across the 8 member slots (lane bits 3,4,5).
    #pragma unroll
    for (int d = 8; d <= 32; d <<= 1) {
        #pragma unroll
        for (int k = 0; k < 8; ++k) {
            acc[k] = fmaxf(acc[k], __shfl_xor(acc[k], d, 64));
        }
    }

    if (lane < 8) {
        float* op = out + (size_t)seg * FEAT + (lane << 3);
        *(float4*)(op)     = make_float4(acc[0], acc[1], acc[2], acc[3]);
        *(float4*)(op + 4) = make_float4(acc[4], acc[5], acc[6], acc[7]);
    }
}

// ---------- fp32 fallback path (used only if ws is too small) ----------
__global__ __launch_bounds__(256)
void seg_starts_kernel(const int* __restrict__ segment_ids,
                       int* __restrict__ starts,
                       int n_members, int num_segments) {
    const int j = blockIdx.x * blockDim.x + threadIdx.x;
    if (j >= n_members) return;
    const int sj = segment_ids[j];
    const int sp = (j == 0) ? -1 : segment_ids[j - 1];
    for (int s = sp + 1; s <= sj; ++s) starts[s] = j;
    if (j == n_members - 1) {
        for (int s = sj + 1; s <= num_segments; ++s) starts[s] = n_members;
    }
}

__global__ __launch_bounds__(64 * SEGS_PER_BLOCK)
void hyper_max_f32(const float* __restrict__ features,
                   const int* __restrict__ node_ids,
                   const int* __restrict__ starts,
                   float* __restrict__ out,
                   int num_segments) {
    const int wave = threadIdx.x >> 6;
    const int lane = threadIdx.x & 63;
    const int seg  = blockIdx.x * SEGS_PER_BLOCK + wave;
    if (seg >= num_segments) return;
    const int start = starts[seg];
    const int end   = starts[seg + 1];
    const int mslot = lane >> 4;
    const int fq    = (lane & 15) << 2;
    float4 acc = make_float4(-INFINITY, -INFINITY, -INFINITY, -INFINITY);
    for (int j = start + mslot; j < end; j += 4) {
        const int n0 = node_ids[j];
        const float4 v = *(const float4*)(features + (size_t)n0 * FEAT + fq);
        acc.x = fmaxf(acc.x, v.x); acc.y = fmaxf(acc.y, v.y);
        acc.z = fmaxf(acc.z, v.z); acc.w = fmaxf(acc.w, v.w);
    }
    acc.x = fmaxf(acc.x, __shfl_xor(acc.x, 16, 64));
    acc.y = fmaxf(acc.y, __shfl_xor(acc.y, 16, 64));
    acc.z = fmaxf(acc.z, __shfl_xor(acc.z, 16, 64));
    acc.w = fmaxf(acc.w, __shfl_xor(acc.w, 16, 64));
    acc.x = fmaxf(acc.x, __shfl_xor(acc.x, 32, 64));
    acc.y = fmaxf(acc.y, __shfl_xor(acc.y, 32, 64));
    acc.z = fmaxf(acc.z, __shfl_xor(acc.z, 32, 64));
    acc.w = fmaxf(acc.w, __shfl_xor(acc.w, 32, 64));
    if (lane < 16) *(float4*)(out + (size_t)seg * FEAT + fq) = acc;
}

extern "C" void kernel_launch(void* const* d_in, const int* in_sizes, int n_in,
                              void* d_out, int out_size, void* d_ws, size_t ws_size,
                              hipStream_t stream) {
    const float* features    = (const float*)d_in[0];
    const int*   node_ids    = (const int*)d_in[1];
    const int*   segment_ids = (const int*)d_in[2];
    float* out = (float*)d_out;

    const int n_elems      = in_sizes[0];         // N_NODES * FEAT
    const int n_members    = in_sizes[1];
    const int num_segments = out_size / FEAT;

    const size_t starts_bytes = (((size_t)(num_segments + 1) * 4) + 255) & ~(size_t)255;
    const size_t bf_bytes     = (size_t)n_elems * 2;
    int* starts = (int*)d_ws;

    const int seg_blocks = (num_segments + SEGS_PER_BLOCK - 1) / SEGS_PER_BLOCK;

    if (ws_size >= starts_bytes + bf_bytes) {
        ushort* feat_bf = (ushort*)((char*)d_ws + starts_bytes);
        const int conv_blocks   = ((n_elems >> 3) + 255) / 256;
        const int starts_blocks = (((n_members + 3) >> 2) + 255) / 256;
        pre_kernel<<<conv_blocks + starts_blocks, 256, 0, stream>>>(
            features, segment_ids, feat_bf, starts,
            conv_blocks, n_elems, n_members, num_segments);
        HyperedgeMaxAggregator_kernel<<<seg_blocks, 64 * SEGS_PER_BLOCK, 0, stream>>>(
            feat_bf, node_ids, starts, out, num_segments);
    } else {
        seg_starts_kernel<<<(n_members + 255) / 256, 256, 0, stream>>>(
            segment_ids, starts, n_members, num_segments);
        hyper_max_f32<<<seg_blocks, 64 * SEGS_PER_BLOCK, 0, stream>>>(
            features, node_ids, starts, out, num_segments);
    }
}